// Round 11
// baseline (96.232 us; speedup 1.0000x reference)
//
#include <hip/hip_runtime.h>
#include <math.h>

// Problem constants
#define BB 8
#define CC 3
#define DD 24
#define HH 128
#define WW 128
#define HW (HH * WW)
#define OCC 16
#define HOUT 126
#define WOUT 126

// Kernel 1: transpose weights [oc][tap] -> [tap][oc] into d_ws so each tap's
// 16 oc-weights are contiguous (64 B) -> wave-uniform float4 loads become
// s_load_dwordx4/x16 and weights live in SGPRs (v_fmac_f32 takes 1 SGPR op).
__global__ void wtrans_kernel(const float* __restrict__ wt,
                              float* __restrict__ wT) {
  const int i = blockIdx.x * 256 + threadIdx.x;
  if (i < 81 * 16) {
    const int tap = i >> 4;
    const int oc = i & 15;
    wT[i] = wt[oc * 81 + tap];
  }
}

// Load one slice's x-tile: CN depths x 3 rows x 4 cols (CN*6 float2).
template <int CN>
__device__ __forceinline__ void load_tile(float2 (&q)[CN][3][2],
                                          const float* __restrict__ p) {
#pragma unroll
  for (int d = 0; d < CN; ++d) {
#pragma unroll
    for (int r = 0; r < 3; ++r) {
      const float* rp = p + (size_t)d * HW + r * WW;
      q[d][r][0] = *reinterpret_cast<const float2*>(rp);
      q[d][r][1] = *reinterpret_cast<const float2*>(rp + 2);
    }
  }
}

// One slice's FMAs (288*CN) from an already-loaded tile; weights via
// wave-uniform s_loads, 48 dwords (3 taps) live at a time.
template <int CN>
__device__ __forceinline__ void comp_slice(const float2 (&q)[CN][3][2],
                                           const float* __restrict__ wsl,
                                           float (&y0)[CN][OCC],
                                           float (&y1)[CN][OCC]) {
#pragma unroll
  for (int r = 0; r < 3; ++r) {  // kh row
    const float* wp = wsl + r * 48;
#pragma unroll
    for (int kw = 0; kw < 3; ++kw) {
      const float4 wA = *reinterpret_cast<const float4*>(wp + kw * 16 + 0);
      const float4 wB = *reinterpret_cast<const float4*>(wp + kw * 16 + 4);
      const float4 wC = *reinterpret_cast<const float4*>(wp + kw * 16 + 8);
      const float4 wD = *reinterpret_cast<const float4*>(wp + kw * 16 + 12);
#pragma unroll
      for (int d = 0; d < CN; ++d) {
        const float xa = (kw == 0) ? q[d][r][0].x : (kw == 1) ? q[d][r][0].y : q[d][r][1].x;
        const float xb = (kw == 0) ? q[d][r][0].y : (kw == 1) ? q[d][r][1].x : q[d][r][1].y;
        y0[d][0]  = fmaf(xa, wA.x, y0[d][0]);  y1[d][0]  = fmaf(xb, wA.x, y1[d][0]);
        y0[d][1]  = fmaf(xa, wA.y, y0[d][1]);  y1[d][1]  = fmaf(xb, wA.y, y1[d][1]);
        y0[d][2]  = fmaf(xa, wA.z, y0[d][2]);  y1[d][2]  = fmaf(xb, wA.z, y1[d][2]);
        y0[d][3]  = fmaf(xa, wA.w, y0[d][3]);  y1[d][3]  = fmaf(xb, wA.w, y1[d][3]);
        y0[d][4]  = fmaf(xa, wB.x, y0[d][4]);  y1[d][4]  = fmaf(xb, wB.x, y1[d][4]);
        y0[d][5]  = fmaf(xa, wB.y, y0[d][5]);  y1[d][5]  = fmaf(xb, wB.y, y1[d][5]);
        y0[d][6]  = fmaf(xa, wB.z, y0[d][6]);  y1[d][6]  = fmaf(xb, wB.z, y1[d][6]);
        y0[d][7]  = fmaf(xa, wB.w, y0[d][7]);  y1[d][7]  = fmaf(xb, wB.w, y1[d][7]);
        y0[d][8]  = fmaf(xa, wC.x, y0[d][8]);  y1[d][8]  = fmaf(xb, wC.x, y1[d][8]);
        y0[d][9]  = fmaf(xa, wC.y, y0[d][9]);  y1[d][9]  = fmaf(xb, wC.y, y1[d][9]);
        y0[d][10] = fmaf(xa, wC.z, y0[d][10]); y1[d][10] = fmaf(xb, wC.z, y1[d][10]);
        y0[d][11] = fmaf(xa, wC.w, y0[d][11]); y1[d][11] = fmaf(xb, wC.w, y1[d][11]);
        y0[d][12] = fmaf(xa, wD.x, y0[d][12]); y1[d][12] = fmaf(xb, wD.x, y1[d][12]);
        y0[d][13] = fmaf(xa, wD.y, y0[d][13]); y1[d][13] = fmaf(xb, wD.y, y1[d][13]);
        y0[d][14] = fmaf(xa, wD.z, y0[d][14]); y1[d][14] = fmaf(xb, wD.z, y1[d][14]);
        y0[d][15] = fmaf(xa, wD.w, y0[d][15]); y1[d][15] = fmaf(xb, wD.w, y1[d][15]);
      }
    }
  }
}

// Process CN consecutive depths.
// ROUND 11: slice-level PING-PONG x prefetch — tile for slice s+1 is issued
// before slice s's 576-cycle FMA block, so its vmcnt is satisfied ~1152
// issue-cycles before use (r10 residual: ~470-cyc x-wait at every slice
// head, lockstep across waves). Two named tile sets, no copies (rule #20:
// all indices compile-time). CN=2 keeps VGPR <= 128 (occupancy cliff, m69).
template <int CN>
__device__ __forceinline__ void conv_chunk(const float* __restrict__ xbase,
                                           const float* __restrict__ wT,
                                           float* __restrict__ mn0,
                                           float* __restrict__ mn1) {
  float y0[CN][OCC], y1[CN][OCC];
#pragma unroll
  for (int d = 0; d < CN; ++d)
#pragma unroll
    for (int oc = 0; oc < OCC; ++oc) { y0[d][oc] = 0.f; y1[d][oc] = 0.f; }

  float2 qa[CN][3][2], qb[CN][3][2];
  const float* ps = xbase;  // slice 0 = (c=0, kd=0)
  load_tile<CN>(qa, ps);

  // Slices 0..8; stride into next slice: +HW, except +(DD-2)*HW after s==2
  // and s==5 (kd 2 -> next c). Pairs (0,1),(2,3),(4,5),(6,7); tail s=8.
#pragma clang loop unroll(disable)
  for (int t = 0; t < 4; ++t) {
    const int s0 = 2 * t;
    const float* ps1 =
        ps + ((s0 == 2) ? (size_t)(DD - 2) * HW : (size_t)HW);
    load_tile<CN>(qb, ps1);                       // prefetch slice s0+1
    comp_slice<CN>(qa, wT + s0 * 144, y0, y1);    // compute slice s0
    const float* ps2 =
        ps1 + ((s0 == 4) ? (size_t)(DD - 2) * HW : (size_t)HW);
    load_tile<CN>(qa, ps2);                       // prefetch slice s0+2
    comp_slice<CN>(qb, wT + (s0 + 1) * 144, y0, y1);  // compute slice s0+1
    ps = ps2;
  }
  comp_slice<CN>(qa, wT + 8 * 144, y0, y1);       // slice 8

#pragma unroll
  for (int d = 0; d < CN; ++d)
#pragma unroll
    for (int oc = 0; oc < OCC; ++oc) {
      mn0[oc] = fminf(mn0[oc], y0[d][oc]);
      mn1[oc] = fminf(mn1[oc], y1[d][oc]);
    }
}

// Kernel 2: 256-thread blocks = 4 waves; wave g covers dz {0-5,6-11,12-16,
// 17-21} as chunks of 2 (+1 tail for g>=2). Each lane: 2 adjacent output
// columns (w0 = 2*lane), all 16 channels. 1-D grid, b = wgid&7 pins each
// batch to one XCD (round 7: FETCH 130->18.5 MB). Waves 1..3 publish partial
// mins to LDS; wave 0 merges + softmax + stores.
__global__ __launch_bounds__(256) void conv_min_softmax_kernel(
    const float* __restrict__ x, const float* __restrict__ wT,
    float* __restrict__ out) {
  __shared__ float sm[3][OCC][WOUT];  // 24.2 KB

  const int tid = threadIdx.x;
  const int lane = tid & 63;
  const int g = tid >> 6;  // wave id 0..3
  const int wg = blockIdx.x;
  const int b = wg & 7;    // XCD selector: all h-blocks of batch b -> XCD b
  const int h = wg >> 3;   // 0..125
  const bool active = (lane < 63);          // 63 lanes cover w0 = 0..124
  const int w0 = 2 * (active ? lane : 62);  // clamp inactive lane's addresses

  // dz ranges per wave: {0-5, 6-11, 12-16, 17-21}
  const int dz0 = (g < 2) ? 6 * g : 12 + 5 * (g - 2);

  const float* xw =
      x + (((size_t)b * CC * DD + dz0) * HH + h) * (size_t)WW + w0;

  float mn0[OCC], mn1[OCC];
#pragma unroll
  for (int oc = 0; oc < OCC; ++oc) { mn0[oc] = INFINITY; mn1[oc] = INFINITY; }

  conv_chunk<2>(xw, wT, mn0, mn1);
  conv_chunk<2>(xw + 2 * (size_t)HW, wT, mn0, mn1);
  if (g < 2) {
    conv_chunk<2>(xw + 4 * (size_t)HW, wT, mn0, mn1);
  } else {
    conv_chunk<1>(xw + 4 * (size_t)HW, wT, mn0, mn1);
  }

  // Waves 1..3 publish partial mins ([oc][w] layout: lanes at w0=2*lane ->
  // 2-way bank aliasing, free).
  if (g > 0 && active) {
#pragma unroll
    for (int oc = 0; oc < OCC; ++oc) {
      sm[g - 1][oc][w0] = mn0[oc];
      sm[g - 1][oc][w0 + 1] = mn1[oc];
    }
  }
  __syncthreads();

  if (g == 0 && active) {
#pragma unroll
    for (int oc = 0; oc < OCC; ++oc) {
      mn0[oc] = fminf(fminf(mn0[oc], sm[0][oc][w0]),
                      fminf(sm[1][oc][w0], sm[2][oc][w0]));
      mn1[oc] = fminf(fminf(mn1[oc], sm[0][oc][w0 + 1]),
                      fminf(sm[1][oc][w0 + 1], sm[2][oc][w0 + 1]));
    }
    float mx0 = mn0[0], mx1 = mn1[0];
#pragma unroll
    for (int oc = 1; oc < OCC; ++oc) {
      mx0 = fmaxf(mx0, mn0[oc]);
      mx1 = fmaxf(mx1, mn1[oc]);
    }
    float e0[OCC], e1[OCC];
    float s0 = 0.f, s1 = 0.f;
#pragma unroll
    for (int oc = 0; oc < OCC; ++oc) {
      e0[oc] = __expf(mn0[oc] - mx0); s0 += e0[oc];
      e1[oc] = __expf(mn1[oc] - mx1); s1 += e1[oc];
    }
    const float i0 = 1.f / s0;
    const float i1 = 1.f / s1;

    float* ob = out + ((size_t)b * OCC * HOUT + h) * (size_t)WOUT + w0;
    const size_t os = (size_t)HOUT * WOUT;
#pragma unroll
    for (int oc = 0; oc < OCC; ++oc) {
      float2 v;
      v.x = e0[oc] * i0;
      v.y = e1[oc] * i1;
      *reinterpret_cast<float2*>(ob + oc * os) = v;  // w0 even -> 8B aligned
    }
  }
}

extern "C" void kernel_launch(void* const* d_in, const int* in_sizes, int n_in,
                              void* d_out, int out_size, void* d_ws, size_t ws_size,
                              hipStream_t stream) {
  const float* x = (const float*)d_in[0];
  const float* wt = (const float*)d_in[1];
  float* out = (float*)d_out;
  float* wT = (float*)d_ws;  // 81*16 floats = 5184 B scratch

  wtrans_kernel<<<dim3(6), dim3(256), 0, stream>>>(wt, wT);

  dim3 grid(1008);          // 1-D: wgid&7 = batch = XCD, wgid>>3 = h
  dim3 block(256, 1, 1);    // 4 waves, dz chunks 2+2+(2|1), Wtile=2
  conv_min_softmax_kernel<<<grid, block, 0, stream>>>(x, wT, out);
}

// Round 12
// 83.759 us; speedup vs baseline: 1.1489x; 1.1489x over previous
//
#include <hip/hip_runtime.h>
#include <math.h>

// Problem constants
#define BB 8
#define CC 3
#define DD 24
#define HH 128
#define WW 128
#define HW (HH * WW)
#define OCC 16
#define HOUT 126
#define WOUT 126

// Kernel 1: transpose weights [oc][tap] -> [tap][oc] into d_ws so each tap's
// 16 oc-weights are contiguous (64 B) -> wave-uniform float4 loads become
// s_load_dwordx4/x16 and weights live in SGPRs (v_fmac_f32 takes 1 SGPR op).
__global__ void wtrans_kernel(const float* __restrict__ wt,
                              float* __restrict__ wT) {
  const int i = blockIdx.x * 256 + threadIdx.x;
  if (i < 81 * 16) {
    const int tap = i >> 4;
    const int oc = i & 15;
    wT[i] = wt[oc * 81 + tap];
  }
}

// Process CN consecutive depths for one wave (r10 structure, unchanged):
// weights s_loaded once per (slice,kh) feed CN depths; x-loads hoisted to
// slice level (one vmcnt wait per 1728 issue-cycles at CN=3).
template <int CN>
__device__ __forceinline__ void conv_chunk(const float* __restrict__ xbase,
                                           const float* __restrict__ wT,
                                           float* __restrict__ mn0,
                                           float* __restrict__ mn1) {
  float y0[CN][OCC], y1[CN][OCC];
#pragma unroll
  for (int d = 0; d < CN; ++d)
#pragma unroll
    for (int oc = 0; oc < OCC; ++oc) { y0[d][oc] = 0.f; y1[d][oc] = 0.f; }

  const float* ps = xbase;  // slice (c=0, kd=0) at depth dz0
#pragma clang loop unroll(disable)
  for (int s = 0; s < 9; ++s) {  // slice = (c, kd)
    // Load the whole slice x-tile: CN depths x 3 rows x 4 cols.
    float2 q[CN][3][2];
#pragma unroll
    for (int d = 0; d < CN; ++d) {
#pragma unroll
      for (int r = 0; r < 3; ++r) {
        const float* rp = ps + (size_t)d * HW + r * WW;
        q[d][r][0] = *reinterpret_cast<const float2*>(rp);
        q[d][r][1] = *reinterpret_cast<const float2*>(rp + 2);
      }
    }
    const float* wsl = wT + s * 144;
#pragma unroll
    for (int r = 0; r < 3; ++r) {  // kh row
      const float* wp = wsl + r * 48;  // wave-uniform -> SGPRs
#pragma unroll
      for (int kw = 0; kw < 3; ++kw) {
        const float4 wA = *reinterpret_cast<const float4*>(wp + kw * 16 + 0);
        const float4 wB = *reinterpret_cast<const float4*>(wp + kw * 16 + 4);
        const float4 wC = *reinterpret_cast<const float4*>(wp + kw * 16 + 8);
        const float4 wD = *reinterpret_cast<const float4*>(wp + kw * 16 + 12);
#pragma unroll
        for (int d = 0; d < CN; ++d) {
          const float xa = (kw == 0) ? q[d][r][0].x : (kw == 1) ? q[d][r][0].y : q[d][r][1].x;
          const float xb = (kw == 0) ? q[d][r][0].y : (kw == 1) ? q[d][r][1].x : q[d][r][1].y;
          y0[d][0]  = fmaf(xa, wA.x, y0[d][0]);  y1[d][0]  = fmaf(xb, wA.x, y1[d][0]);
          y0[d][1]  = fmaf(xa, wA.y, y0[d][1]);  y1[d][1]  = fmaf(xb, wA.y, y1[d][1]);
          y0[d][2]  = fmaf(xa, wA.z, y0[d][2]);  y1[d][2]  = fmaf(xb, wA.z, y1[d][2]);
          y0[d][3]  = fmaf(xa, wA.w, y0[d][3]);  y1[d][3]  = fmaf(xb, wA.w, y1[d][3]);
          y0[d][4]  = fmaf(xa, wB.x, y0[d][4]);  y1[d][4]  = fmaf(xb, wB.x, y1[d][4]);
          y0[d][5]  = fmaf(xa, wB.y, y0[d][5]);  y1[d][5]  = fmaf(xb, wB.y, y1[d][5]);
          y0[d][6]  = fmaf(xa, wB.z, y0[d][6]);  y1[d][6]  = fmaf(xb, wB.z, y1[d][6]);
          y0[d][7]  = fmaf(xa, wB.w, y0[d][7]);  y1[d][7]  = fmaf(xb, wB.w, y1[d][7]);
          y0[d][8]  = fmaf(xa, wC.x, y0[d][8]);  y1[d][8]  = fmaf(xb, wC.x, y1[d][8]);
          y0[d][9]  = fmaf(xa, wC.y, y0[d][9]);  y1[d][9]  = fmaf(xb, wC.y, y1[d][9]);
          y0[d][10] = fmaf(xa, wC.z, y0[d][10]); y1[d][10] = fmaf(xb, wC.z, y1[d][10]);
          y0[d][11] = fmaf(xa, wC.w, y0[d][11]); y1[d][11] = fmaf(xb, wC.w, y1[d][11]);
          y0[d][12] = fmaf(xa, wD.x, y0[d][12]); y1[d][12] = fmaf(xb, wD.x, y1[d][12]);
          y0[d][13] = fmaf(xa, wD.y, y0[d][13]); y1[d][13] = fmaf(xb, wD.y, y1[d][13]);
          y0[d][14] = fmaf(xa, wD.z, y0[d][14]); y1[d][14] = fmaf(xb, wD.z, y1[d][14]);
          y0[d][15] = fmaf(xa, wD.w, y0[d][15]); y1[d][15] = fmaf(xb, wD.w, y1[d][15]);
        }
      }
    }
    // advance slice: kd step = HW; (c,2)->(c+1,0) step = (DD-2)*HW
    ps += (s == 2 || s == 5) ? (size_t)(DD - 2) * HW : (size_t)HW;
  }

#pragma unroll
  for (int d = 0; d < CN; ++d)
#pragma unroll
    for (int oc = 0; oc < OCC; ++oc) {
      mn0[oc] = fminf(mn0[oc], y0[d][oc]);
      mn1[oc] = fminf(mn1[oc], y1[d][oc]);
    }
}

// Kernel 2 (r10 structure + ROUND 12 time-stagger): 256-thread blocks =
// 4 waves; wave g covers dz {0-5,6-11,12-16,17-21} as chunks 3+3 / 3+2.
// Each lane: 2 adjacent output columns, all 16 channels. 1-D grid, b=wg&7
// pins each batch to one XCD. ROUND 12: all resident waves run identical-
// length code and therefore stall on vmcnt/lgkm at the SAME instants —
// TLP can't hide the ~970 cyc/slice exposure (r6/r10 evidence). Prologue
// s_sleep stagger (slot*192 cyc; slot distinct across the 4 waves AND the
// ~4 co-resident blocks of a CU via wg>>8) decorrelates the stall times so
// other waves' FMAs cover each wave's waits.
__global__ __launch_bounds__(256) void conv_min_softmax_kernel(
    const float* __restrict__ x, const float* __restrict__ wT,
    float* __restrict__ out) {
  __shared__ float sm[3][OCC][WOUT];  // 24.2 KB

  const int tid = threadIdx.x;
  const int lane = tid & 63;
  const int g = tid >> 6;  // wave id 0..3
  const int wg = blockIdx.x;

  // Time-stagger: slot 0..15 unique among the 16 waves resident on a CU.
  // Same-CU blocks are wg, wg+256, wg+512, wg+768 -> (wg>>8)&3 in 0..3.
  {
    const int slot = g * 4 + ((wg >> 8) & 3);
    const int nsleep = slot * 3;  // 3 x 64 = 192 cyc per slot
#pragma clang loop unroll(disable)
    for (int i = 0; i < nsleep; ++i) __builtin_amdgcn_s_sleep(1);
  }

  const int b = wg & 7;    // XCD selector: all h-blocks of batch b -> XCD b
  const int h = wg >> 3;   // 0..125
  const bool active = (lane < 63);          // 63 lanes cover w0 = 0..124
  const int w0 = 2 * (active ? lane : 62);  // clamp inactive lane's addresses

  // dz ranges per wave: {0-5, 6-11, 12-16, 17-21}
  const int dz0 = (g < 2) ? 6 * g : 12 + 5 * (g - 2);

  const float* xw =
      x + (((size_t)b * CC * DD + dz0) * HH + h) * (size_t)WW + w0;

  float mn0[OCC], mn1[OCC];
#pragma unroll
  for (int oc = 0; oc < OCC; ++oc) { mn0[oc] = INFINITY; mn1[oc] = INFINITY; }

  conv_chunk<3>(xw, wT, mn0, mn1);
  if (g < 2) {
    conv_chunk<3>(xw + 3 * (size_t)HW, wT, mn0, mn1);
  } else {
    conv_chunk<2>(xw + 3 * (size_t)HW, wT, mn0, mn1);
  }

  // Waves 1..3 publish partial mins ([oc][w] layout: lanes at w0=2*lane ->
  // 2-way bank aliasing, free).
  if (g > 0 && active) {
#pragma unroll
    for (int oc = 0; oc < OCC; ++oc) {
      sm[g - 1][oc][w0] = mn0[oc];
      sm[g - 1][oc][w0 + 1] = mn1[oc];
    }
  }
  __syncthreads();

  if (g == 0 && active) {
#pragma unroll
    for (int oc = 0; oc < OCC; ++oc) {
      mn0[oc] = fminf(fminf(mn0[oc], sm[0][oc][w0]),
                      fminf(sm[1][oc][w0], sm[2][oc][w0]));
      mn1[oc] = fminf(fminf(mn1[oc], sm[0][oc][w0 + 1]),
                      fminf(sm[1][oc][w0 + 1], sm[2][oc][w0 + 1]));
    }
    float mx0 = mn0[0], mx1 = mn1[0];
#pragma unroll
    for (int oc = 1; oc < OCC; ++oc) {
      mx0 = fmaxf(mx0, mn0[oc]);
      mx1 = fmaxf(mx1, mn1[oc]);
    }
    float e0[OCC], e1[OCC];
    float s0 = 0.f, s1 = 0.f;
#pragma unroll
    for (int oc = 0; oc < OCC; ++oc) {
      e0[oc] = __expf(mn0[oc] - mx0); s0 += e0[oc];
      e1[oc] = __expf(mn1[oc] - mx1); s1 += e1[oc];
    }
    const float i0 = 1.f / s0;
    const float i1 = 1.f / s1;

    float* ob = out + ((size_t)b * OCC * HOUT + h) * (size_t)WOUT + w0;
    const size_t os = (size_t)HOUT * WOUT;
#pragma unroll
    for (int oc = 0; oc < OCC; ++oc) {
      float2 v;
      v.x = e0[oc] * i0;
      v.y = e1[oc] * i1;
      *reinterpret_cast<float2*>(ob + oc * os) = v;  // w0 even -> 8B aligned
    }
  }
}

extern "C" void kernel_launch(void* const* d_in, const int* in_sizes, int n_in,
                              void* d_out, int out_size, void* d_ws, size_t ws_size,
                              hipStream_t stream) {
  const float* x = (const float*)d_in[0];
  const float* wt = (const float*)d_in[1];
  float* out = (float*)d_out;
  float* wT = (float*)d_ws;  // 81*16 floats = 5184 B scratch

  wtrans_kernel<<<dim3(6), dim3(256), 0, stream>>>(wt, wT);

  dim3 grid(1008);          // 1-D: wgid&7 = batch = XCD, wgid>>3 = h
  dim3 block(256, 1, 1);    // 4 waves, dz chunks 3+3 / 3+2, Wtile=2
  conv_min_softmax_kernel<<<grid, block, 0, stream>>>(x, wT, out);
}

// Round 13
// 81.713 us; speedup vs baseline: 1.1777x; 1.0250x over previous
//
#include <hip/hip_runtime.h>
#include <math.h>

// Problem constants
#define BB 8
#define CC 3
#define DD 24
#define HH 128
#define WW 128
#define HW (HH * WW)
#define OCC 16
#define HOUT 126
#define WOUT 126

// Kernel 1: transpose weights [oc][tap] -> [tap][oc] into d_ws so each tap's
// 16 oc-weights are contiguous (64 B) -> wave-uniform float4 loads become
// s_load_dwordx4/x16 and weights live in SGPRs (v_fmac_f32 takes 1 SGPR op).
__global__ void wtrans_kernel(const float* __restrict__ wt,
                              float* __restrict__ wT) {
  const int i = blockIdx.x * 256 + threadIdx.x;
  if (i < 81 * 16) {
    const int tap = i >> 4;
    const int oc = i & 15;
    wT[i] = wt[oc * 81 + tap];
  }
}

// Process CN consecutive depths for one wave.
// ROUND 13: c-group PLANE CACHING. Per input channel c, load the CN+2
// contiguous depth-planes (3 rows x 4 cols each) ONCE into registers
// (q[CN+2][3][2]), then run all 3 kd-slices (3*288*CN FMAs) from them.
// r10 reloaded each slice's 3-plane window -> 54 float2/chunk whose 2/3
// "L1 reuse" thrashed (96 KB working set vs 32 KB L1) -> all hit L2 at
// ~85 B/cyc/CU demand vs ~56 ceiling (the r10-r12 stall; stagger null
// refuted latency-correlation). Now 30 f2/c-group (x0.56 traffic), and
// stall points drop 9->3 per chunk with 5184-cyc FMA runs between.
template <int CN>
__device__ __forceinline__ void conv_chunk(const float* __restrict__ xbase,
                                           const float* __restrict__ wT,
                                           float* __restrict__ mn0,
                                           float* __restrict__ mn1) {
  float y0[CN][OCC], y1[CN][OCC];
#pragma unroll
  for (int d = 0; d < CN; ++d)
#pragma unroll
    for (int oc = 0; oc < OCC; ++oc) { y0[d][oc] = 0.f; y1[d][oc] = 0.f; }

#pragma clang loop unroll(disable)
  for (int c = 0; c < 3; ++c) {  // input channel (runtime loop: bounds regs)
    const float* pc = xbase + (size_t)c * DD * HW;
    // Load CN+2 contiguous planes x 3 rows x 4 cols into registers.
    float2 q[CN + 2][3][2];
#pragma unroll
    for (int p = 0; p < CN + 2; ++p) {
#pragma unroll
      for (int r = 0; r < 3; ++r) {
        const float* rp = pc + (size_t)p * HW + r * WW;
        q[p][r][0] = *reinterpret_cast<const float2*>(rp);
        q[p][r][1] = *reinterpret_cast<const float2*>(rp + 2);
      }
    }
#pragma unroll
    for (int kd = 0; kd < 3; ++kd) {  // slice = (c, kd)
      const float* wsl = wT + (c * 3 + kd) * 144;
#pragma unroll
      for (int r = 0; r < 3; ++r) {  // kh row
        const float* wp = wsl + r * 48;  // wave-uniform -> SGPRs
#pragma unroll
        for (int kw = 0; kw < 3; ++kw) {
          const float4 wA = *reinterpret_cast<const float4*>(wp + kw * 16 + 0);
          const float4 wB = *reinterpret_cast<const float4*>(wp + kw * 16 + 4);
          const float4 wC = *reinterpret_cast<const float4*>(wp + kw * 16 + 8);
          const float4 wD = *reinterpret_cast<const float4*>(wp + kw * 16 + 12);
#pragma unroll
          for (int d = 0; d < CN; ++d) {
            // output depth dz0+d uses input plane kd+d (all compile-time)
            const float xa = (kw == 0) ? q[kd + d][r][0].x
                           : (kw == 1) ? q[kd + d][r][0].y : q[kd + d][r][1].x;
            const float xb = (kw == 0) ? q[kd + d][r][0].y
                           : (kw == 1) ? q[kd + d][r][1].x : q[kd + d][r][1].y;
            y0[d][0]  = fmaf(xa, wA.x, y0[d][0]);  y1[d][0]  = fmaf(xb, wA.x, y1[d][0]);
            y0[d][1]  = fmaf(xa, wA.y, y0[d][1]);  y1[d][1]  = fmaf(xb, wA.y, y1[d][1]);
            y0[d][2]  = fmaf(xa, wA.z, y0[d][2]);  y1[d][2]  = fmaf(xb, wA.z, y1[d][2]);
            y0[d][3]  = fmaf(xa, wA.w, y0[d][3]);  y1[d][3]  = fmaf(xb, wA.w, y1[d][3]);
            y0[d][4]  = fmaf(xa, wB.x, y0[d][4]);  y1[d][4]  = fmaf(xb, wB.x, y1[d][4]);
            y0[d][5]  = fmaf(xa, wB.y, y0[d][5]);  y1[d][5]  = fmaf(xb, wB.y, y1[d][5]);
            y0[d][6]  = fmaf(xa, wB.z, y0[d][6]);  y1[d][6]  = fmaf(xb, wB.z, y1[d][6]);
            y0[d][7]  = fmaf(xa, wB.w, y0[d][7]);  y1[d][7]  = fmaf(xb, wB.w, y1[d][7]);
            y0[d][8]  = fmaf(xa, wC.x, y0[d][8]);  y1[d][8]  = fmaf(xb, wC.x, y1[d][8]);
            y0[d][9]  = fmaf(xa, wC.y, y0[d][9]);  y1[d][9]  = fmaf(xb, wC.y, y1[d][9]);
            y0[d][10] = fmaf(xa, wC.z, y0[d][10]); y1[d][10] = fmaf(xb, wC.z, y1[d][10]);
            y0[d][11] = fmaf(xa, wC.w, y0[d][11]); y1[d][11] = fmaf(xb, wC.w, y1[d][11]);
            y0[d][12] = fmaf(xa, wD.x, y0[d][12]); y1[d][12] = fmaf(xb, wD.x, y1[d][12]);
            y0[d][13] = fmaf(xa, wD.y, y0[d][13]); y1[d][13] = fmaf(xb, wD.y, y1[d][13]);
            y0[d][14] = fmaf(xa, wD.z, y0[d][14]); y1[d][14] = fmaf(xb, wD.z, y1[d][14]);
            y0[d][15] = fmaf(xa, wD.w, y0[d][15]); y1[d][15] = fmaf(xb, wD.w, y1[d][15]);
          }
        }
      }
    }
  }

#pragma unroll
  for (int d = 0; d < CN; ++d)
#pragma unroll
    for (int oc = 0; oc < OCC; ++oc) {
      mn0[oc] = fminf(mn0[oc], y0[d][oc]);
      mn1[oc] = fminf(mn1[oc], y1[d][oc]);
    }
}

// Kernel 2: 256-thread blocks = 4 waves; wave g covers dz {0-5,6-11,12-16,
// 17-21} as chunks 3+3 / 3+2. Each lane: 2 adjacent output columns
// (w0 = 2*lane), all 16 channels. 1-D grid, b = wgid&7 pins each batch to
// one XCD (round 7: FETCH 130->18.5 MB). Waves 1..3 publish partial mins to
// LDS; wave 0 merges + softmax + stores.
__global__ __launch_bounds__(256) void conv_min_softmax_kernel(
    const float* __restrict__ x, const float* __restrict__ wT,
    float* __restrict__ out) {
  __shared__ float sm[3][OCC][WOUT];  // 24.2 KB

  const int tid = threadIdx.x;
  const int lane = tid & 63;
  const int g = tid >> 6;  // wave id 0..3
  const int wg = blockIdx.x;
  const int b = wg & 7;    // XCD selector: all h-blocks of batch b -> XCD b
  const int h = wg >> 3;   // 0..125
  const bool active = (lane < 63);          // 63 lanes cover w0 = 0..124
  const int w0 = 2 * (active ? lane : 62);  // clamp inactive lane's addresses

  // dz ranges per wave: {0-5, 6-11, 12-16, 17-21}
  const int dz0 = (g < 2) ? 6 * g : 12 + 5 * (g - 2);

  const float* xw =
      x + (((size_t)b * CC * DD + dz0) * HH + h) * (size_t)WW + w0;

  float mn0[OCC], mn1[OCC];
#pragma unroll
  for (int oc = 0; oc < OCC; ++oc) { mn0[oc] = INFINITY; mn1[oc] = INFINITY; }

  conv_chunk<3>(xw, wT, mn0, mn1);
  if (g < 2) {
    conv_chunk<3>(xw + 3 * (size_t)HW, wT, mn0, mn1);
  } else {
    conv_chunk<2>(xw + 3 * (size_t)HW, wT, mn0, mn1);
  }

  // Waves 1..3 publish partial mins ([oc][w] layout: lanes at w0=2*lane ->
  // 2-way bank aliasing, free).
  if (g > 0 && active) {
#pragma unroll
    for (int oc = 0; oc < OCC; ++oc) {
      sm[g - 1][oc][w0] = mn0[oc];
      sm[g - 1][oc][w0 + 1] = mn1[oc];
    }
  }
  __syncthreads();

  if (g == 0 && active) {
#pragma unroll
    for (int oc = 0; oc < OCC; ++oc) {
      mn0[oc] = fminf(fminf(mn0[oc], sm[0][oc][w0]),
                      fminf(sm[1][oc][w0], sm[2][oc][w0]));
      mn1[oc] = fminf(fminf(mn1[oc], sm[0][oc][w0 + 1]),
                      fminf(sm[1][oc][w0 + 1], sm[2][oc][w0 + 1]));
    }
    float mx0 = mn0[0], mx1 = mn1[0];
#pragma unroll
    for (int oc = 1; oc < OCC; ++oc) {
      mx0 = fmaxf(mx0, mn0[oc]);
      mx1 = fmaxf(mx1, mn1[oc]);
    }
    float e0[OCC], e1[OCC];
    float s0 = 0.f, s1 = 0.f;
#pragma unroll
    for (int oc = 0; oc < OCC; ++oc) {
      e0[oc] = __expf(mn0[oc] - mx0); s0 += e0[oc];
      e1[oc] = __expf(mn1[oc] - mx1); s1 += e1[oc];
    }
    const float i0 = 1.f / s0;
    const float i1 = 1.f / s1;

    float* ob = out + ((size_t)b * OCC * HOUT + h) * (size_t)WOUT + w0;
    const size_t os = (size_t)HOUT * WOUT;
#pragma unroll
    for (int oc = 0; oc < OCC; ++oc) {
      float2 v;
      v.x = e0[oc] * i0;
      v.y = e1[oc] * i1;
      *reinterpret_cast<float2*>(ob + oc * os) = v;  // w0 even -> 8B aligned
    }
  }
}

extern "C" void kernel_launch(void* const* d_in, const int* in_sizes, int n_in,
                              void* d_out, int out_size, void* d_ws, size_t ws_size,
                              hipStream_t stream) {
  const float* x = (const float*)d_in[0];
  const float* wt = (const float*)d_in[1];
  float* out = (float*)d_out;
  float* wT = (float*)d_ws;  // 81*16 floats = 5184 B scratch

  wtrans_kernel<<<dim3(6), dim3(256), 0, stream>>>(wt, wT);

  dim3 grid(1008);          // 1-D: wgid&7 = batch = XCD, wgid>>3 = h
  dim3 block(256, 1, 1);    // 4 waves, dz chunks 3+3 / 3+2, Wtile=2
  conv_min_softmax_kernel<<<grid, block, 0, stream>>>(x, wT, out);
}